// Round 1
// baseline (116.292 us; speedup 1.0000x reference)
//
#include <hip/hip_runtime.h>
#include <math.h>

// Problem constants (fixed by setup_inputs)
#define BATCH   2
#define NS      8192
#define NT      2048
#define KNN     64
#define PP      3
#define CH      64
#define NSH     16
#define NSHELL  3
#define SC      (NSHELL*CH)   // 192
#define YROW    (NSH*SC)      // 3072 floats per (b,n) point
#define KSTR    52            // padded LDS stride (floats) for kern rows (16B-aligned, odd/32 bank walk)

// ---------------------------------------------------------------------------
// Kernel 1: SH-Gaussian kernels + neighbor gather + contraction
//   y[b,n,ys, s*64+c] = (1/K) * sum_k sh_k[ys] * w_k[s] * feats[idx_k][c]
// One 256-thread block per (b,n) point. 4096 blocks.
// ---------------------------------------------------------------------------
__global__ __launch_bounds__(256) void sh_conv_kernel(
    const float* __restrict__ src,      // (B,NS,CH)
    const float* __restrict__ patches,  // (B,NT,K,3)
    const float* __restrict__ pdist,    // (B,NT,K)
    const int*   __restrict__ pidx,     // (B,NT,K)
    float* __restrict__ y)              // (B,NT,16,192)
{
    __shared__ float kern[KNN * KSTR];   // 13312 B
    __shared__ float feats[KNN * CH];    // 16384 B

    const int pt = blockIdx.x;           // b*NT + n
    const int b  = pt / NT;
    const int t  = threadIdx.x;

    // ---- Phase A1: gather neighbor features into LDS ----
    {
        const int* idx_base = pidx + pt * KNN;
        const int kk = t >> 4;           // 0..15
        const int c4 = (t & 15) * 4;
        #pragma unroll
        for (int pass = 0; pass < 4; ++pass) {
            const int k  = pass * 16 + kk;
            const int id = idx_base[k];
            const float4 v = *(const float4*)(src + ((size_t)(b * NS + id)) * CH + c4);
            *(float4*)&feats[k * CH + c4] = v;
        }
    }

    // ---- Phase A2: compute kern[k][ys*3+s] = sh[ys]*w[s] ----
    {
        const int k = t & 63;
        const int q = t >> 6;            // quarter: ys rows 4q..4q+3
        const float* pv = patches + ((size_t)pt * KNN + k) * 3;
        const float px = pv[0], py = pv[1], pz = pv[2];
        const float d  = pdist[pt * KNN + k];
        const float inv = 1.0f / (d + 1e-8f);
        const float x = px * inv, yy = py * inv, z = pz * inv;
        const float x2 = x * x, y2 = yy * yy, z2 = z * z;

        float sh[16];
        sh[0]  = 0.28209479177387814f;
        sh[1]  = 0.4886025119029199f * yy;
        sh[2]  = 0.4886025119029199f * z;
        sh[3]  = 0.4886025119029199f * x;
        sh[4]  = 1.0925484305920792f * x * yy;
        sh[5]  = 1.0925484305920792f * yy * z;
        sh[6]  = 0.31539156525252005f * (3.0f * z2 - 1.0f);
        sh[7]  = 1.0925484305920792f * x * z;
        sh[8]  = 0.5462742152960396f * (x2 - y2);
        sh[9]  = 0.5900435899266435f * yy * (3.0f * x2 - y2);
        sh[10] = 2.890611442640554f  * x * yy * z;
        sh[11] = 0.4570457994644658f * yy * (5.0f * z2 - 1.0f);
        sh[12] = 0.3731763325901154f * z * (5.0f * z2 - 3.0f);
        sh[13] = 0.4570457994644658f * x * (5.0f * z2 - 1.0f);
        sh[14] = 1.445305721320277f  * z * (x2 - y2);
        sh[15] = 0.5900435899266435f * x * (x2 - 3.0f * y2);

        const float GS = 6.23832462504f;            // ln2 * 9
        float w0 = expf(-GS * d * d);
        const float dm1 = d - 0.5f;
        float w1 = expf(-GS * dm1 * dm1);
        const float dm2 = d - 1.0f;
        float w2 = expf(-GS * dm2 * dm2);
        const float wn = 1.0f / (w0 + w1 + w2 + 1e-8f);
        const float bound = (d <= 1.0f) ? 1.0f : 0.0f;
        w0 *= wn * bound; w1 *= wn * bound; w2 *= wn * bound;

        #pragma unroll
        for (int i = 0; i < 4; ++i) {
            const int ys = q * 4 + i;
            const float s = sh[ys];
            kern[k * KSTR + ys * 3 + 0] = s * w0;
            kern[k * KSTR + ys * 3 + 1] = s * w1;
            kern[k * KSTR + ys * 3 + 2] = s * w2;
        }
    }
    __syncthreads();

    // ---- Phase B: accumulate. Thread owns ys = t>>4, s=0..2, c = c0..c0+3 ----
    const int c0 = (t & 15) * 4;
    const int g  = t >> 4;               // ys index 0..15
    const int rg = g * 3;                // kern row base (rows rg..rg+2 all have ys=g, s=0..2)
    float acc[3][4] = {{0.f,0.f,0.f,0.f},{0.f,0.f,0.f,0.f},{0.f,0.f,0.f,0.f}};

    #pragma unroll 8
    for (int k = 0; k < KNN; ++k) {
        const float4 f = *(const float4*)&feats[k * CH + c0];
        const float k0 = kern[k * KSTR + rg + 0];
        const float k1 = kern[k * KSTR + rg + 1];
        const float k2 = kern[k * KSTR + rg + 2];
        acc[0][0] += k0 * f.x; acc[0][1] += k0 * f.y; acc[0][2] += k0 * f.z; acc[0][3] += k0 * f.w;
        acc[1][0] += k1 * f.x; acc[1][1] += k1 * f.y; acc[1][2] += k1 * f.z; acc[1][3] += k1 * f.w;
        acc[2][0] += k2 * f.x; acc[2][1] += k2 * f.y; acc[2][2] += k2 * f.z; acc[2][3] += k2 * f.w;
    }

    const float invK = 1.0f / 64.0f;
    float* yb = y + (size_t)pt * YROW + g * SC + c0;
    #pragma unroll
    for (int s = 0; s < 3; ++s) {
        float4 o;
        o.x = acc[s][0] * invK; o.y = acc[s][1] * invK;
        o.z = acc[s][2] * invK; o.w = acc[s][3] * invK;
        *(float4*)(yb + s * CH) = o;
    }
}

// ---------------------------------------------------------------------------
// Kernel 2: inverse-square-distance propagation + per-degree norms
// One 192-thread block per (b,ns) source point; thread = one sc column.
// ---------------------------------------------------------------------------
__global__ __launch_bounds__(192) void prop_norm_kernel(
    const float* __restrict__ y,         // (B,NT,16,192)
    const int*   __restrict__ prop_idx,  // (B,NS,3)
    const float* __restrict__ prop_dist, // (B,NS,3)
    float* __restrict__ out)             // (B,NS,768)
{
    const int pt = blockIdx.x;           // b*NS + ns
    const int b  = pt >> 13;             // NS = 8192
    const int sc = threadIdx.x;          // 0..191

    const int   i0 = prop_idx[pt * 3 + 0];
    const int   i1 = prop_idx[pt * 3 + 1];
    const int   i2 = prop_idx[pt * 3 + 2];
    const float d0 = prop_dist[pt * 3 + 0];
    const float d1 = prop_dist[pt * 3 + 1];
    const float d2 = prop_dist[pt * 3 + 2];

    float w0 = 1.0f / (d0 * d0 + 1e-8f);
    float w1 = 1.0f / (d1 * d1 + 1e-8f);
    float w2 = 1.0f / (d2 * d2 + 1e-8f);
    const float wi = 1.0f / (w0 + w1 + w2);
    w0 *= wi; w1 *= wi; w2 *= wi;

    const float* y0 = y + ((size_t)(b * NT + i0)) * YROW + sc;
    const float* y1 = y + ((size_t)(b * NT + i1)) * YROW + sc;
    const float* y2 = y + ((size_t)(b * NT + i2)) * YROW + sc;

    float nsum[4] = {0.f, 0.f, 0.f, 0.f};
    #pragma unroll
    for (int ys = 0; ys < NSH; ++ys) {
        const float v = w0 * y0[ys * SC] + w1 * y1[ys * SC] + w2 * y2[ys * SC];
        const int l = (ys == 0) ? 0 : (ys < 4) ? 1 : (ys < 9) ? 2 : 3;
        nsum[l] += v * v;
    }

    float* ob = out + (size_t)pt * (4 * SC) + sc;
    #pragma unroll
    for (int l = 0; l < 4; ++l)
        ob[l * SC] = sqrtf(fmaxf(nsum[l], 1e-8f));
}

// ---------------------------------------------------------------------------
extern "C" void kernel_launch(void* const* d_in, const int* in_sizes, int n_in,
                              void* d_out, int out_size, void* d_ws, size_t ws_size,
                              hipStream_t stream) {
    const float* src       = (const float*)d_in[0];  // source_feats (B,NS,CH)
    const float* patches   = (const float*)d_in[1];  // (B,NT,K,3)
    const float* pdist     = (const float*)d_in[2];  // (B,NT,K)
    const int*   pidx      = (const int*)d_in[3];    // (B,NT,K)
    const int*   prop_idx  = (const int*)d_in[4];    // (B,NS,PP)
    const float* prop_dist = (const float*)d_in[5];  // (B,NS,PP)
    float*       out       = (float*)d_out;          // (B,NS,768)
    float*       y_ws      = (float*)d_ws;           // (B,NT,16,192) = 50.3 MB

    sh_conv_kernel<<<BATCH * NT, 256, 0, stream>>>(src, patches, pdist, pidx, y_ws);
    prop_norm_kernel<<<BATCH * NS, 192, 0, stream>>>(y_ws, prop_idx, prop_dist, out);
}

// Round 2
// 74.452 us; speedup vs baseline: 1.5620x; 1.5620x over previous
//
#include <hip/hip_runtime.h>
#include <math.h>

// Problem constants (fixed by setup_inputs)
#define BATCH   2
#define NS      8192
#define NT      2048
#define KNN     64
#define PP      3
#define CH      64
#define NSH     16
#define NSHELL  3
#define SC      (NSHELL*CH)   // 192
#define YROW    (NSH*SC)      // 3072 elements per (b,n) point
#define KST2    68            // padded LDS stride for transposed kern rows

// round-to-nearest-even float -> bf16 bits
__device__ inline unsigned short f2bf(float x) {
    unsigned u = __float_as_uint(x);
    unsigned r = (u + 0x7fffu + ((u >> 16) & 1u)) >> 16;
    return (unsigned short)r;
}
__device__ inline float blo(unsigned v) { return __uint_as_float(v << 16); }
__device__ inline float bhi(unsigned v) { return __uint_as_float(v & 0xffff0000u); }

// ---------------------------------------------------------------------------
// Kernel 1: SH-Gaussian kernels + neighbor gather + contraction
//   y[b,n,ys, s*64+c] = (1/K) * sum_k sh_k[ys] * w_k[s] * feats[idx_k][c]
// One 256-thread block per (b,n) point. 4096 blocks. y stored bf16.
// ---------------------------------------------------------------------------
__global__ __launch_bounds__(256) void sh_conv_kernel(
    const float* __restrict__ src,      // (B,NS,CH)
    const float* __restrict__ patches,  // (B,NT,K,3)
    const float* __restrict__ pdist,    // (B,NT,K)
    const int*   __restrict__ pidx,     // (B,NT,K)
    unsigned short* __restrict__ y)     // (B,NT,16,192) bf16
{
    __shared__ float kern2[48 * KST2];   // [row=ys*3+s][k], 13056 B
    __shared__ float feats[KNN * CH];    // 16384 B

    const int pt = blockIdx.x;           // b*NT + n
    const int b  = pt / NT;
    const int t  = threadIdx.x;

    // ---- Phase A1: gather neighbor features into LDS ----
    {
        const int* idx_base = pidx + pt * KNN;
        const int kk = t >> 4;           // 0..15
        const int c4 = (t & 15) * 4;
        #pragma unroll
        for (int pass = 0; pass < 4; ++pass) {
            const int k  = pass * 16 + kk;
            const int id = idx_base[k];
            const float4 v = *(const float4*)(src + ((size_t)(b * NS + id)) * CH + c4);
            *(float4*)&feats[k * CH + c4] = v;
        }
    }

    // ---- Phase A2: compute kern2[(ys*3+s)][k] = sh[ys]*w[s] ----
    {
        const int k = t & 63;
        const int q = t >> 6;            // quarter: ys rows 4q..4q+3
        const float* pv = patches + ((size_t)pt * KNN + k) * 3;
        const float px = pv[0], py = pv[1], pz = pv[2];
        const float d  = pdist[pt * KNN + k];
        const float inv = 1.0f / (d + 1e-8f);
        const float x = px * inv, yy = py * inv, z = pz * inv;
        const float x2 = x * x, y2 = yy * yy, z2 = z * z;

        float sh[16];
        sh[0]  = 0.28209479177387814f;
        sh[1]  = 0.4886025119029199f * yy;
        sh[2]  = 0.4886025119029199f * z;
        sh[3]  = 0.4886025119029199f * x;
        sh[4]  = 1.0925484305920792f * x * yy;
        sh[5]  = 1.0925484305920792f * yy * z;
        sh[6]  = 0.31539156525252005f * (3.0f * z2 - 1.0f);
        sh[7]  = 1.0925484305920792f * x * z;
        sh[8]  = 0.5462742152960396f * (x2 - y2);
        sh[9]  = 0.5900435899266435f * yy * (3.0f * x2 - y2);
        sh[10] = 2.890611442640554f  * x * yy * z;
        sh[11] = 0.4570457994644658f * yy * (5.0f * z2 - 1.0f);
        sh[12] = 0.3731763325901154f * z * (5.0f * z2 - 3.0f);
        sh[13] = 0.4570457994644658f * x * (5.0f * z2 - 1.0f);
        sh[14] = 1.445305721320277f  * z * (x2 - y2);
        sh[15] = 0.5900435899266435f * x * (x2 - 3.0f * y2);

        const float GS = 6.23832462504f;            // ln2 * 9
        float w0 = expf(-GS * d * d);
        const float dm1 = d - 0.5f;
        float w1 = expf(-GS * dm1 * dm1);
        const float dm2 = d - 1.0f;
        float w2 = expf(-GS * dm2 * dm2);
        const float wn = 1.0f / (w0 + w1 + w2 + 1e-8f);
        const float bound = (d <= 1.0f) ? 1.0f : 0.0f;
        w0 *= wn * bound; w1 *= wn * bound; w2 *= wn * bound;

        #pragma unroll
        for (int i = 0; i < 4; ++i) {
            const int ys = q * 4 + i;
            const float s = sh[ys];
            kern2[(ys * 3 + 0) * KST2 + k] = s * w0;
            kern2[(ys * 3 + 1) * KST2 + k] = s * w1;
            kern2[(ys * 3 + 2) * KST2 + k] = s * w2;
        }
    }
    __syncthreads();

    // ---- Phase B: accumulate. Thread owns ys = t>>4, s=0..2, c = c0..c0+3 ----
    const int c0 = (t & 15) * 4;
    const int g  = t >> 4;               // ys index 0..15
    const int rg = g * 3;                // kern2 row base
    float acc[3][4] = {{0.f,0.f,0.f,0.f},{0.f,0.f,0.f,0.f},{0.f,0.f,0.f,0.f}};

    #pragma unroll 4
    for (int k4 = 0; k4 < KNN; k4 += 4) {
        const float4 kv0 = *(const float4*)&kern2[(rg + 0) * KST2 + k4];
        const float4 kv1 = *(const float4*)&kern2[(rg + 1) * KST2 + k4];
        const float4 kv2 = *(const float4*)&kern2[(rg + 2) * KST2 + k4];
        const float k0a[4] = {kv0.x, kv0.y, kv0.z, kv0.w};
        const float k1a[4] = {kv1.x, kv1.y, kv1.z, kv1.w};
        const float k2a[4] = {kv2.x, kv2.y, kv2.z, kv2.w};
        #pragma unroll
        for (int kk = 0; kk < 4; ++kk) {
            const float4 f = *(const float4*)&feats[(k4 + kk) * CH + c0];
            const float k0 = k0a[kk], k1 = k1a[kk], k2 = k2a[kk];
            acc[0][0] += k0 * f.x; acc[0][1] += k0 * f.y; acc[0][2] += k0 * f.z; acc[0][3] += k0 * f.w;
            acc[1][0] += k1 * f.x; acc[1][1] += k1 * f.y; acc[1][2] += k1 * f.z; acc[1][3] += k1 * f.w;
            acc[2][0] += k2 * f.x; acc[2][1] += k2 * f.y; acc[2][2] += k2 * f.z; acc[2][3] += k2 * f.w;
        }
    }

    const float invK = 1.0f / 64.0f;
    unsigned short* yb = y + (size_t)pt * YROW + g * SC + c0;
    #pragma unroll
    for (int s = 0; s < 3; ++s) {
        uint2 o;
        o.x = (unsigned)f2bf(acc[s][0] * invK) | ((unsigned)f2bf(acc[s][1] * invK) << 16);
        o.y = (unsigned)f2bf(acc[s][2] * invK) | ((unsigned)f2bf(acc[s][3] * invK) << 16);
        *(uint2*)(yb + s * CH) = o;
    }
}

// ---------------------------------------------------------------------------
// Kernel 2: inverse-square-distance propagation + per-degree norms
// 192-thread block = 8 source points x 24 threads; thread owns 8 sc columns,
// loads ushort8 (16B) per (neighbor, ys).
// ---------------------------------------------------------------------------
__global__ __launch_bounds__(192) void prop_norm_kernel(
    const unsigned short* __restrict__ y, // (B,NT,16,192) bf16
    const int*   __restrict__ prop_idx,   // (B,NS,3)
    const float* __restrict__ prop_dist,  // (B,NS,3)
    float* __restrict__ out)              // (B,NS,768)
{
    const int t  = threadIdx.x;
    const int lp = t / 24;                // local point 0..7
    const int u  = t % 24;                // sc-group: columns 8u..8u+7
    const int pt = blockIdx.x * 8 + lp;   // b*NS + ns
    const int b  = pt >> 13;              // NS = 8192

    const int   i0 = prop_idx[pt * 3 + 0];
    const int   i1 = prop_idx[pt * 3 + 1];
    const int   i2 = prop_idx[pt * 3 + 2];
    const float d0 = prop_dist[pt * 3 + 0];
    const float d1 = prop_dist[pt * 3 + 1];
    const float d2 = prop_dist[pt * 3 + 2];

    float w0 = 1.0f / (d0 * d0 + 1e-8f);
    float w1 = 1.0f / (d1 * d1 + 1e-8f);
    float w2 = 1.0f / (d2 * d2 + 1e-8f);
    const float wi = 1.0f / (w0 + w1 + w2);
    w0 *= wi; w1 *= wi; w2 *= wi;

    const unsigned short* y0 = y + ((size_t)(b * NT + i0)) * YROW + u * 8;
    const unsigned short* y1 = y + ((size_t)(b * NT + i1)) * YROW + u * 8;
    const unsigned short* y2 = y + ((size_t)(b * NT + i2)) * YROW + u * 8;

    float nsum[4][8];
    #pragma unroll
    for (int l = 0; l < 4; ++l)
        #pragma unroll
        for (int j = 0; j < 8; ++j) nsum[l][j] = 0.f;

    #pragma unroll
    for (int ys = 0; ys < NSH; ++ys) {
        const uint4 ua = *(const uint4*)(y0 + ys * SC);
        const uint4 ub = *(const uint4*)(y1 + ys * SC);
        const uint4 uc = *(const uint4*)(y2 + ys * SC);
        const int l = (ys == 0) ? 0 : (ys < 4) ? 1 : (ys < 9) ? 2 : 3;
        const unsigned a[4] = {ua.x, ua.y, ua.z, ua.w};
        const unsigned bb[4] = {ub.x, ub.y, ub.z, ub.w};
        const unsigned c[4] = {uc.x, uc.y, uc.z, uc.w};
        #pragma unroll
        for (int q = 0; q < 4; ++q) {
            const float vlo = w0 * blo(a[q]) + w1 * blo(bb[q]) + w2 * blo(c[q]);
            const float vhi = w0 * bhi(a[q]) + w1 * bhi(bb[q]) + w2 * bhi(c[q]);
            nsum[l][2 * q]     += vlo * vlo;
            nsum[l][2 * q + 1] += vhi * vhi;
        }
    }

    float* ob = out + (size_t)pt * (4 * SC) + u * 8;
    #pragma unroll
    for (int l = 0; l < 4; ++l) {
        float4 o0, o1;
        o0.x = sqrtf(fmaxf(nsum[l][0], 1e-8f));
        o0.y = sqrtf(fmaxf(nsum[l][1], 1e-8f));
        o0.z = sqrtf(fmaxf(nsum[l][2], 1e-8f));
        o0.w = sqrtf(fmaxf(nsum[l][3], 1e-8f));
        o1.x = sqrtf(fmaxf(nsum[l][4], 1e-8f));
        o1.y = sqrtf(fmaxf(nsum[l][5], 1e-8f));
        o1.z = sqrtf(fmaxf(nsum[l][6], 1e-8f));
        o1.w = sqrtf(fmaxf(nsum[l][7], 1e-8f));
        *(float4*)(ob + l * SC)     = o0;
        *(float4*)(ob + l * SC + 4) = o1;
    }
}

// ---------------------------------------------------------------------------
extern "C" void kernel_launch(void* const* d_in, const int* in_sizes, int n_in,
                              void* d_out, int out_size, void* d_ws, size_t ws_size,
                              hipStream_t stream) {
    const float* src       = (const float*)d_in[0];  // source_feats (B,NS,CH)
    const float* patches   = (const float*)d_in[1];  // (B,NT,K,3)
    const float* pdist     = (const float*)d_in[2];  // (B,NT,K)
    const int*   pidx      = (const int*)d_in[3];    // (B,NT,K)
    const int*   prop_idx  = (const int*)d_in[4];    // (B,NS,PP)
    const float* prop_dist = (const float*)d_in[5];  // (B,NS,PP)
    float*       out       = (float*)d_out;          // (B,NS,768)
    unsigned short* y_ws   = (unsigned short*)d_ws;  // (B,NT,16,192) bf16 = 25 MB

    sh_conv_kernel<<<BATCH * NT, 256, 0, stream>>>(src, patches, pdist, pidx, y_ws);
    prop_norm_kernel<<<(BATCH * NS) / 8, 192, 0, stream>>>(y_ws, prop_idx, prop_dist, out);
}